// Round 5
// baseline (235.963 us; speedup 1.0000x reference)
//
#include <hip/hip_runtime.h>

typedef unsigned short u16;
typedef unsigned int   u32;

typedef short short8 __attribute__((ext_vector_type(8)));
typedef float floatx4 __attribute__((ext_vector_type(4)));

#define CDIM 128
#define K_NEG_LOG2E -1.4426950408889634f

__device__ __forceinline__ float bf2f_lo(u32 h) {
    union { u32 u; float f; } v; v.u = h << 16; return v.f;
}
__device__ __forceinline__ float bf2f_hi(u32 h) {
    union { u32 u; float f; } v; v.u = h & 0xffff0000u; return v.f;
}
__device__ __forceinline__ u16 f2bf(float f) {
    union { float f; u32 u; } v; v.f = f;
    u32 u = v.u;
    return (u16)((u + 0x7FFFu + ((u >> 16) & 1u)) >> 16);  // RNE
}
// standard sigmoid (final kernel only)
__device__ __forceinline__ float sig_std(float x) {
    return __builtin_amdgcn_rcpf(1.0f + __builtin_amdgcn_exp2f(x * K_NEG_LOG2E));
}

// One launch: zero sum/cnt pairs AND convert both weight matrices to bf16
// pre-scaled by -log2(e).
__global__ __launch_bounds__(256) void prep_kernel(
    const float* __restrict__ Wstu, const float* __restrict__ Witem,
    u32* __restrict__ Wbf_pair, float4* __restrict__ zero4, int nZero4)
{
    const int tid = blockIdx.x * blockDim.x + threadIdx.x;
    const int stride = gridDim.x * blockDim.x;
    // 2 * 128*128 floats = 16384 u32 pairs (first 8192 = Wstu, rest = Witem)
    for (int i = tid; i < 16384; i += stride) {
        const float* W = (i & 8192) ? (Witem - 16384) : Wstu;  // adjust base
        const int j = i * 2;
        u32 lo = f2bf(W[j]     * K_NEG_LOG2E);
        u32 hi = f2bf(W[j + 1] * K_NEG_LOG2E);
        Wbf_pair[i] = lo | (hi << 16);
    }
    const float4 z = {0.f, 0.f, 0.f, 0.f};
    for (int i = tid; i < nZero4; i += stride) zero4[i] = z;
}

// One wave computes a 32-row tile; stores exp2(proj + bias) in bf16
// (exp2 domain: edge kernel then needs no transcendental except one rcp).
__device__ __forceinline__ void proj_tile32(
    const float* __restrict__ X, const u16* __restrict__ Wbf,
    const float* __restrict__ bias, u16* __restrict__ out,
    int nrows, int ostride, int ooff, int row0, int lane)
{
    const int m = lane & 15;   // A-row / B-col / D-col
    const int g = lane >> 4;   // k-quad

    short8 a[2][4];
#pragma unroll
    for (int t = 0; t < 2; ++t) {
        int arow = row0 + t * 16 + m;
        if (arow >= nrows) arow = nrows - 1;   // clamp; stores masked below
        const float* xrow = X + (size_t)arow * CDIM;
#pragma unroll
        for (int s = 0; s < 4; ++s) {
            float4 f0 = *(const float4*)(xrow + s * 32 + g * 8);
            float4 f1 = *(const float4*)(xrow + s * 32 + g * 8 + 4);
            a[t][s][0] = (short)f2bf(f0.x); a[t][s][1] = (short)f2bf(f0.y);
            a[t][s][2] = (short)f2bf(f0.z); a[t][s][3] = (short)f2bf(f0.w);
            a[t][s][4] = (short)f2bf(f1.x); a[t][s][5] = (short)f2bf(f1.y);
            a[t][s][6] = (short)f2bf(f1.z); a[t][s][7] = (short)f2bf(f1.w);
        }
    }

#pragma unroll
    for (int ct = 0; ct < 8; ++ct) {
        const u16* wrow = Wbf + (size_t)(ct * 16 + m) * CDIM;
        floatx4 acc0 = {0.f, 0.f, 0.f, 0.f};
        floatx4 acc1 = {0.f, 0.f, 0.f, 0.f};
#pragma unroll
        for (int s = 0; s < 4; ++s) {
            short8 b = *(const short8*)(wrow + s * 32 + g * 8);
            acc0 = __builtin_amdgcn_mfma_f32_16x16x32_bf16(a[0][s], b, acc0, 0, 0, 0);
            acc1 = __builtin_amdgcn_mfma_f32_16x16x32_bf16(a[1][s], b, acc1, 0, 0, 0);
        }
        const int col = ct * 16 + m;           // D: col = lane&15
        const float badd = bias ? bias[col] * K_NEG_LOG2E : 0.f;
#pragma unroll
        for (int i = 0; i < 4; ++i) {
            int r0 = row0 + g * 4 + i;         // D: row = (lane>>4)*4 + reg
            if (r0 < nrows)
                out[(size_t)r0 * ostride + ooff + col] =
                    f2bf(__builtin_amdgcn_exp2f(acc0[i] + badd));
            int r1 = r0 + 16;
            if (r1 < nrows)
                out[(size_t)r1 * ostride + ooff + col] =
                    f2bf(__builtin_amdgcn_exp2f(acc1[i] + badd));
        }
    }
}

// All four projections in one launch; wave-uniform segment select.
__global__ __launch_bounds__(256) void proj4_kernel(
    const float* __restrict__ stu_x, const float* __restrict__ item_x,
    const float* __restrict__ conc_x,
    const u16* __restrict__ Wstu_bf, const u16* __restrict__ Witem_bf,
    const float* __restrict__ b_stu, const float* __restrict__ b_item,
    u16* __restrict__ stu_p, u16* __restrict__ item_p, u16* __restrict__ conc_cat,
    int NS, int NI, int NC)
{
    const int lane = threadIdx.x & 63;
    int w = blockIdx.x * 4 + (threadIdx.x >> 6);
    const int T0 = (NS + 31) / 32, T1 = (NI + 31) / 32, T2 = (NC + 31) / 32;

    if (w < T0) { proj_tile32(stu_x, Wstu_bf, nullptr, stu_p, NS, 128, 0, w * 32, lane); return; }
    w -= T0;
    if (w < T1) { proj_tile32(item_x, Witem_bf, nullptr, item_p, NI, 128, 0, w * 32, lane); return; }
    w -= T1;
    if (w < T2) { proj_tile32(conc_x, Wstu_bf, b_stu, conc_cat, NC, 256, 0, w * 32, lane); return; }
    w -= T2;
    if (w < T2) { proj_tile32(conc_x, Witem_bf, b_item, conc_cat, NC, 256, 128, w * 32, lane); return; }
}

// 16 lanes per edge, 4 edges per wave. Tables hold E = 2^(pre-scaled proj);
// sigma(a)-sigma(b) = (eb-ea)/(1+ea+eb+ea*eb): 1 rcp per channel-pair, no exp.
// Depth-1 register prefetch of gather data, depth-2 for indices.
__global__ __launch_bounds__(256) void edge_kernel(
    const u16* __restrict__ stu_p, const u16* __restrict__ item_p,
    const u16* __restrict__ conc_cat,
    const int* __restrict__ stu_track, const int* __restrict__ item_index,
    const int* __restrict__ conc_index, const int* __restrict__ mean_index,
    const float* __restrict__ w_pred,
    float* __restrict__ sc, int E)   // sc[2*m] = sum, sc[2*m+1] = cnt
{
    const int lane = threadIdx.x & 63;
    const int sub  = lane & 15;      // position within edge
    const int g    = lane >> 4;      // edge within quad
    const int waveId = (int)((blockIdx.x * blockDim.x + threadIdx.x) >> 6);
    const int nWaves = (int)((gridDim.x * blockDim.x) >> 6);

    const float4 wA = ((const float4*)w_pred)[sub * 2];
    const float4 wB = ((const float4*)w_pred)[sub * 2 + 1];
    const float w8[8] = {wA.x, wA.y, wA.z, wA.w, wB.x, wB.y, wB.z, wB.w};
    const u32 lane_off = (u32)sub * 16;

    const int nQuads = (E + 3) >> 2;
    int q = waveId;
    if (q >= nQuads) return;

#define LOADIDX(qq, sN, iN, cN, mN, lN) { \
        int e_ = (qq) * 4 + g; int ec_ = (e_ < E) ? e_ : (E - 1); \
        lN = (e_ < E); \
        sN = stu_track[ec_]; iN = item_index[ec_]; \
        cN = conc_index[ec_]; mN = mean_index[ec_]; }

#define GATHER(si_, ii_, ci_, sv_, iv_, ca_, cb_) { \
        sv_ = *(const uint4*)((const char*)stu_p  + (((u32)(si_) << 8) + lane_off)); \
        iv_ = *(const uint4*)((const char*)item_p + (((u32)(ii_) << 8) + lane_off)); \
        const char* cp_ = (const char*)conc_cat + (((u32)(ci_) << 9) + lane_off); \
        ca_ = *(const uint4*)cp_; cb_ = *(const uint4*)(cp_ + 256); }

    // pipeline preamble
    int si, ii, ci, mi; bool live;
    LOADIDX(q, si, ii, ci, mi, live);
    uint4 sv, iv, ca, cb;
    GATHER(si, ii, ci, sv, iv, ca, cb);

    int qn = q + nWaves;
    bool more = (qn < nQuads);
    int si2 = 0, ii2 = 0, ci2 = 0, mi2 = 0; bool live2 = false;
    if (more) LOADIDX(qn, si2, ii2, ci2, mi2, live2);

    while (true) {
        // issue next iteration's gathers before computing (latency overlap)
        uint4 svN, ivN, caN, cbN;
        if (more) GATHER(si2, ii2, ci2, svN, ivN, caN, cbN);

        // prefetch indices two iterations ahead
        const int qnn = qn + nWaves;
        const bool more2 = (qnn < nQuads);
        int si3 = 0, ii3 = 0, ci3 = 0, mi3 = 0; bool live3 = false;
        if (more2) LOADIDX(qnn, si3, ii3, ci3, mi3, live3);

        const u32 su[4] = {sv.x, sv.y, sv.z, sv.w};
        const u32 iu[4] = {iv.x, iv.y, iv.z, iv.w};
        const u32 au[4] = {ca.x, ca.y, ca.z, ca.w};
        const u32 bu[4] = {cb.x, cb.y, cb.z, cb.w};

        float v = 0.f;
#pragma unroll
        for (int j = 0; j < 4; ++j) {
            const float ea0 = bf2f_lo(au[j]) * bf2f_lo(su[j]);
            const float eb0 = bf2f_lo(bu[j]) * bf2f_lo(iu[j]);
            const float ea1 = bf2f_hi(au[j]) * bf2f_hi(su[j]);
            const float eb1 = bf2f_hi(bu[j]) * bf2f_hi(iu[j]);
            const float den0 = 1.0f + fmaf(ea0, eb0, ea0 + eb0);
            const float den1 = 1.0f + fmaf(ea1, eb1, ea1 + eb1);
            v += w8[2 * j]     * ((eb0 - ea0) * __builtin_amdgcn_rcpf(den0));
            v += w8[2 * j + 1] * ((eb1 - ea1) * __builtin_amdgcn_rcpf(den1));
        }

        // reduce within each 16-lane group (masks < 16 stay in-group)
        v += __shfl_xor(v, 1, 64);
        v += __shfl_xor(v, 2, 64);
        v += __shfl_xor(v, 4, 64);
        v += __shfl_xor(v, 8, 64);

        if (sub == 0 && live) {
            atomicAdd(&sc[2 * (size_t)mi], v);       // same 64B line as cnt
            atomicAdd(&sc[2 * (size_t)mi + 1], 1.0f);
        }

        if (!more) break;
        sv = svN; iv = ivN; ca = caN; cb = cbN;
        mi = mi2; live = live2;
        q = qn; qn = qnn;
        si2 = si3; ii2 = ii3; ci2 = ci3; mi2 = mi3; live2 = live3;
        more = more2;
    }
#undef LOADIDX
#undef GATHER
}

__global__ __launch_bounds__(256) void final_kernel(
    const float* __restrict__ sc,
    const float* __restrict__ b_pred, float* __restrict__ out, int M)
{
    const int i = blockIdx.x * blockDim.x + threadIdx.x;
    if (i < M) {
        const float2 p = ((const float2*)sc)[i];
        const float mean = p.x / fmaxf(p.y, 1.0f);
        out[i] = sig_std(mean + b_pred[0]);
    }
}

extern "C" void kernel_launch(void* const* d_in, const int* in_sizes, int n_in,
                              void* d_out, int out_size, void* d_ws, size_t ws_size,
                              hipStream_t stream) {
    const float* stu_x    = (const float*)d_in[0];
    const float* item_x   = (const float*)d_in[1];
    const float* conc_x   = (const float*)d_in[2];
    const float* W_stu    = (const float*)d_in[3];
    const float* b_stu    = (const float*)d_in[4];
    const float* W_item   = (const float*)d_in[5];
    const float* b_item   = (const float*)d_in[6];
    const float* W_pred   = (const float*)d_in[7];
    const float* b_pred   = (const float*)d_in[8];
    const int* stu_track  = (const int*)d_in[9];
    const int* item_index = (const int*)d_in[10];
    const int* conc_index = (const int*)d_in[11];
    const int* mean_index = (const int*)d_in[12];

    const int NS = in_sizes[0] / CDIM;
    const int NI = in_sizes[1] / CDIM;
    const int NC = in_sizes[2] / CDIM;
    const int E  = in_sizes[9];
    const int M  = out_size;

    // workspace layout (all pieces 16B-aligned)
    float* sc      = (float*)d_ws;               // [M] interleaved (sum, cnt)
    u16* Wstu_bf   = (u16*)(sc + 2 * (size_t)M); // Wstu_bf || Witem_bf contiguous
    u16* Witem_bf  = Wstu_bf + CDIM * CDIM;
    u16* stu_p     = Witem_bf + CDIM * CDIM;
    u16* item_p    = stu_p  + (size_t)NS * CDIM;
    u16* conc_cat  = item_p + (size_t)NI * CDIM; // [NC][256]: exp2 stu-side | item-side

    const int nZero4 = (2 * M) / 4;
    prep_kernel<<<512, 256, 0, stream>>>(W_stu, W_item, (u32*)Wstu_bf,
                                         (float4*)sc, nZero4);

    const int T0 = (NS + 31) / 32, T1 = (NI + 31) / 32, T2 = (NC + 31) / 32;
    const int totalWaves = T0 + T1 + 2 * T2;
    proj4_kernel<<<(totalWaves + 3) / 4, 256, 0, stream>>>(
        stu_x, item_x, conc_x, Wstu_bf, Witem_bf, b_stu, b_item,
        stu_p, item_p, conc_cat, NS, NI, NC);

    edge_kernel<<<4096, 256, 0, stream>>>(stu_p, item_p, conc_cat,
                                          stu_track, item_index, conc_index, mean_index,
                                          W_pred, sc, E);

    final_kernel<<<(M + 255) / 256, 256, 0, stream>>>(sc, b_pred, (float*)d_out, M);
}

// Round 6
// 198.590 us; speedup vs baseline: 1.1882x; 1.1882x over previous
//
#include <hip/hip_runtime.h>

typedef unsigned short u16;
typedef unsigned int   u32;

typedef short short8 __attribute__((ext_vector_type(8)));
typedef float floatx4 __attribute__((ext_vector_type(4)));

#define CDIM 128
#define K_NEG_LOG2E -1.4426950408889634f
#define CNT_SCALE 16777216.0   // 2^24: packs (sum, count) into one f64

__device__ __forceinline__ float bf2f_lo(u32 h) {
    union { u32 u; float f; } v; v.u = h << 16; return v.f;
}
__device__ __forceinline__ float bf2f_hi(u32 h) {
    union { u32 u; float f; } v; v.u = h & 0xffff0000u; return v.f;
}
__device__ __forceinline__ u16 f2bf(float f) {
    union { float f; u32 u; } v; v.f = f;
    u32 u = v.u;
    return (u16)((u + 0x7FFFu + ((u >> 16) & 1u)) >> 16);  // RNE
}
// standard sigmoid (final kernel only)
__device__ __forceinline__ float sig_std(float x) {
    return __builtin_amdgcn_rcpf(1.0f + __builtin_amdgcn_exp2f(x * K_NEG_LOG2E));
}

// One launch: zero the f64 accumulators AND convert both weight matrices to
// bf16 pre-scaled by -log2(e).
__global__ __launch_bounds__(256) void prep_kernel(
    const float* __restrict__ Wstu, const float* __restrict__ Witem,
    u32* __restrict__ Wbf_pair, float4* __restrict__ zero4, int nZero4)
{
    const int tid = blockIdx.x * blockDim.x + threadIdx.x;
    const int stride = gridDim.x * blockDim.x;
    for (int i = tid; i < 16384; i += stride) {
        const float* W = (i & 8192) ? (Witem - 16384) : Wstu;
        const int j = i * 2;
        u32 lo = f2bf(W[j]     * K_NEG_LOG2E);
        u32 hi = f2bf(W[j + 1] * K_NEG_LOG2E);
        Wbf_pair[i] = lo | (hi << 16);
    }
    const float4 z = {0.f, 0.f, 0.f, 0.f};
    for (int i = tid; i < nZero4; i += stride) zero4[i] = z;
}

// One wave computes a 32-row tile; stores exp2(proj + bias) in bf16.
__device__ __forceinline__ void proj_tile32(
    const float* __restrict__ X, const u16* __restrict__ Wbf,
    const float* __restrict__ bias, u16* __restrict__ out,
    int nrows, int ostride, int ooff, int row0, int lane)
{
    const int m = lane & 15;   // A-row / B-col / D-col
    const int g = lane >> 4;   // k-quad

    short8 a[2][4];
#pragma unroll
    for (int t = 0; t < 2; ++t) {
        int arow = row0 + t * 16 + m;
        if (arow >= nrows) arow = nrows - 1;   // clamp; stores masked below
        const float* xrow = X + (size_t)arow * CDIM;
#pragma unroll
        for (int s = 0; s < 4; ++s) {
            float4 f0 = *(const float4*)(xrow + s * 32 + g * 8);
            float4 f1 = *(const float4*)(xrow + s * 32 + g * 8 + 4);
            a[t][s][0] = (short)f2bf(f0.x); a[t][s][1] = (short)f2bf(f0.y);
            a[t][s][2] = (short)f2bf(f0.z); a[t][s][3] = (short)f2bf(f0.w);
            a[t][s][4] = (short)f2bf(f1.x); a[t][s][5] = (short)f2bf(f1.y);
            a[t][s][6] = (short)f2bf(f1.z); a[t][s][7] = (short)f2bf(f1.w);
        }
    }

#pragma unroll
    for (int ct = 0; ct < 8; ++ct) {
        const u16* wrow = Wbf + (size_t)(ct * 16 + m) * CDIM;
        floatx4 acc0 = {0.f, 0.f, 0.f, 0.f};
        floatx4 acc1 = {0.f, 0.f, 0.f, 0.f};
#pragma unroll
        for (int s = 0; s < 4; ++s) {
            short8 b = *(const short8*)(wrow + s * 32 + g * 8);
            acc0 = __builtin_amdgcn_mfma_f32_16x16x32_bf16(a[0][s], b, acc0, 0, 0, 0);
            acc1 = __builtin_amdgcn_mfma_f32_16x16x32_bf16(a[1][s], b, acc1, 0, 0, 0);
        }
        const int col = ct * 16 + m;           // D: col = lane&15
        const float badd = bias ? bias[col] * K_NEG_LOG2E : 0.f;
#pragma unroll
        for (int i = 0; i < 4; ++i) {
            int r0 = row0 + g * 4 + i;         // D: row = (lane>>4)*4 + reg
            if (r0 < nrows)
                out[(size_t)r0 * ostride + ooff + col] =
                    f2bf(__builtin_amdgcn_exp2f(acc0[i] + badd));
            int r1 = r0 + 16;
            if (r1 < nrows)
                out[(size_t)r1 * ostride + ooff + col] =
                    f2bf(__builtin_amdgcn_exp2f(acc1[i] + badd));
        }
    }
}

// All four projections in one launch; wave-uniform segment select.
__global__ __launch_bounds__(256) void proj4_kernel(
    const float* __restrict__ stu_x, const float* __restrict__ item_x,
    const float* __restrict__ conc_x,
    const u16* __restrict__ Wstu_bf, const u16* __restrict__ Witem_bf,
    const float* __restrict__ b_stu, const float* __restrict__ b_item,
    u16* __restrict__ stu_p, u16* __restrict__ item_p, u16* __restrict__ conc_cat,
    int NS, int NI, int NC)
{
    const int lane = threadIdx.x & 63;
    int w = blockIdx.x * 4 + (threadIdx.x >> 6);
    const int T0 = (NS + 31) / 32, T1 = (NI + 31) / 32, T2 = (NC + 31) / 32;

    if (w < T0) { proj_tile32(stu_x, Wstu_bf, nullptr, stu_p, NS, 128, 0, w * 32, lane); return; }
    w -= T0;
    if (w < T1) { proj_tile32(item_x, Witem_bf, nullptr, item_p, NI, 128, 0, w * 32, lane); return; }
    w -= T1;
    if (w < T2) { proj_tile32(conc_x, Wstu_bf, b_stu, conc_cat, NC, 256, 0, w * 32, lane); return; }
    w -= T2;
    if (w < T2) { proj_tile32(conc_x, Witem_bf, b_item, conc_cat, NC, 256, 128, w * 32, lane); return; }
}

// 16 lanes per edge, 4 edges per wave. Tables hold E = 2^(pre-scaled proj);
// sigma(a)-sigma(b) = (eb-ea)/(1+ea+eb+ea*eb).
// Software pipeline enforced with sched_barrier; ONE f64 atomic per edge
// carries both sum and count (count in bits >= 2^24).
__global__ __launch_bounds__(256) void edge_kernel(
    const u16* __restrict__ stu_p, const u16* __restrict__ item_p,
    const u16* __restrict__ conc_cat,
    const int* __restrict__ stu_track, const int* __restrict__ item_index,
    const int* __restrict__ conc_index, const int* __restrict__ mean_index,
    const float* __restrict__ w_pred,
    double* __restrict__ sc, int E)
{
    const int lane = threadIdx.x & 63;
    const int sub  = lane & 15;      // position within edge
    const int g    = lane >> 4;      // edge within quad
    const int waveId = (int)((blockIdx.x * blockDim.x + threadIdx.x) >> 6);
    const int nWaves = (int)((gridDim.x * blockDim.x) >> 6);

    const float4 wA = ((const float4*)w_pred)[sub * 2];
    const float4 wB = ((const float4*)w_pred)[sub * 2 + 1];
    const float w8[8] = {wA.x, wA.y, wA.z, wA.w, wB.x, wB.y, wB.z, wB.w};
    const u32 lane_off = (u32)sub * 16;

    const int nQuads = (E + 3) >> 2;
    int q = waveId;
    if (q >= nQuads) return;

#define LOADIDX(qq, sN, iN, cN, mN, lN) { \
        int e_ = (qq) * 4 + g; int ec_ = (e_ < E) ? e_ : (E - 1); \
        lN = (e_ < E); \
        sN = stu_track[ec_]; iN = item_index[ec_]; \
        cN = conc_index[ec_]; mN = mean_index[ec_]; }

#define GATHER(si_, ii_, ci_, sv_, iv_, ca_, cb_) { \
        sv_ = *(const uint4*)((const char*)stu_p  + (((u32)(si_) << 8) + lane_off)); \
        iv_ = *(const uint4*)((const char*)item_p + (((u32)(ii_) << 8) + lane_off)); \
        const char* cp_ = (const char*)conc_cat + (((u32)(ci_) << 9) + lane_off); \
        ca_ = *(const uint4*)cp_; cb_ = *(const uint4*)(cp_ + 256); }

    // pipeline preamble
    int si, ii, ci, mi; bool live;
    LOADIDX(q, si, ii, ci, mi, live);
    uint4 sv, iv, ca, cb;
    GATHER(si, ii, ci, sv, iv, ca, cb);

    int qn = q + nWaves;
    bool more = (qn < nQuads);
    int si2 = 0, ii2 = 0, ci2 = 0, mi2 = 0; bool live2 = false;
    if (more) LOADIDX(qn, si2, ii2, ci2, mi2, live2);

    while (true) {
        // issue next iteration's gathers + next-next indices BEFORE compute
        uint4 svN, ivN, caN, cbN;
        if (more) GATHER(si2, ii2, ci2, svN, ivN, caN, cbN);

        const int qnn = qn + nWaves;
        const bool more2 = (qnn < nQuads);
        int si3 = 0, ii3 = 0, ci3 = 0, mi3 = 0; bool live3 = false;
        if (more2) LOADIDX(qnn, si3, ii3, ci3, mi3, live3);

        // fence: loads above may NOT sink below; compute below waits only on
        // the CURRENT iteration's (older) loads -> vmcnt(N>0), true overlap.
        __builtin_amdgcn_sched_barrier(0);

        const u32 su[4] = {sv.x, sv.y, sv.z, sv.w};
        const u32 iu[4] = {iv.x, iv.y, iv.z, iv.w};
        const u32 au[4] = {ca.x, ca.y, ca.z, ca.w};
        const u32 bu[4] = {cb.x, cb.y, cb.z, cb.w};

        float v = 0.f;
#pragma unroll
        for (int j = 0; j < 4; ++j) {
            const float ea0 = bf2f_lo(au[j]) * bf2f_lo(su[j]);
            const float eb0 = bf2f_lo(bu[j]) * bf2f_lo(iu[j]);
            const float ea1 = bf2f_hi(au[j]) * bf2f_hi(su[j]);
            const float eb1 = bf2f_hi(bu[j]) * bf2f_hi(iu[j]);
            const float den0 = 1.0f + fmaf(ea0, eb0, ea0 + eb0);
            const float den1 = 1.0f + fmaf(ea1, eb1, ea1 + eb1);
            v += w8[2 * j]     * ((eb0 - ea0) * __builtin_amdgcn_rcpf(den0));
            v += w8[2 * j + 1] * ((eb1 - ea1) * __builtin_amdgcn_rcpf(den1));
        }

        // reduce within each 16-lane group
        v += __shfl_xor(v, 1, 64);
        v += __shfl_xor(v, 2, 64);
        v += __shfl_xor(v, 4, 64);
        v += __shfl_xor(v, 8, 64);

        if (sub == 0 && live) {
            // one f64 atomic: sum in low magnitude, count scaled by 2^24
            atomicAdd(&sc[mi], (double)v + CNT_SCALE);
        }

        if (!more) break;
        sv = svN; iv = ivN; ca = caN; cb = cbN;
        mi = mi2; live = live2;
        q = qn; qn = qnn;
        si2 = si3; ii2 = ii3; ci2 = ci3; mi2 = mi3; live2 = live3;
        more = more2;
    }
#undef LOADIDX
#undef GATHER
}

__global__ __launch_bounds__(256) void final_kernel(
    const double* __restrict__ sc,
    const float* __restrict__ b_pred, float* __restrict__ out, int M)
{
    const int i = blockIdx.x * blockDim.x + threadIdx.x;
    if (i < M) {
        const double acc = sc[i];
        const double cnt = rint(acc * (1.0 / CNT_SCALE));   // |sum| << 2^23
        const double sum = acc - cnt * CNT_SCALE;
        const float mean = (float)(sum / fmax(cnt, 1.0));
        out[i] = sig_std(mean + b_pred[0]);
    }
}

extern "C" void kernel_launch(void* const* d_in, const int* in_sizes, int n_in,
                              void* d_out, int out_size, void* d_ws, size_t ws_size,
                              hipStream_t stream) {
    const float* stu_x    = (const float*)d_in[0];
    const float* item_x   = (const float*)d_in[1];
    const float* conc_x   = (const float*)d_in[2];
    const float* W_stu    = (const float*)d_in[3];
    const float* b_stu    = (const float*)d_in[4];
    const float* W_item   = (const float*)d_in[5];
    const float* b_item   = (const float*)d_in[6];
    const float* W_pred   = (const float*)d_in[7];
    const float* b_pred   = (const float*)d_in[8];
    const int* stu_track  = (const int*)d_in[9];
    const int* item_index = (const int*)d_in[10];
    const int* conc_index = (const int*)d_in[11];
    const int* mean_index = (const int*)d_in[12];

    const int NS = in_sizes[0] / CDIM;
    const int NI = in_sizes[1] / CDIM;
    const int NC = in_sizes[2] / CDIM;
    const int E  = in_sizes[9];
    const int M  = out_size;

    // workspace layout (all pieces 16B-aligned)
    double* sc     = (double*)d_ws;              // [M] packed (sum + cnt*2^24)
    u16* Wstu_bf   = (u16*)(sc + M);             // Wstu_bf || Witem_bf contiguous
    u16* Witem_bf  = Wstu_bf + CDIM * CDIM;
    u16* stu_p     = Witem_bf + CDIM * CDIM;
    u16* item_p    = stu_p  + (size_t)NS * CDIM;
    u16* conc_cat  = item_p + (size_t)NI * CDIM; // [NC][256]: exp2 stu | item side

    const int nZero4 = (int)(((size_t)M * sizeof(double)) / 16);
    prep_kernel<<<512, 256, 0, stream>>>(W_stu, W_item, (u32*)Wstu_bf,
                                         (float4*)sc, nZero4);

    const int T0 = (NS + 31) / 32, T1 = (NI + 31) / 32, T2 = (NC + 31) / 32;
    const int totalWaves = T0 + T1 + 2 * T2;
    proj4_kernel<<<(totalWaves + 3) / 4, 256, 0, stream>>>(
        stu_x, item_x, conc_x, Wstu_bf, Witem_bf, b_stu, b_item,
        stu_p, item_p, conc_cat, NS, NI, NC);

    edge_kernel<<<4096, 256, 0, stream>>>(stu_p, item_p, conc_cat,
                                          stu_track, item_index, conc_index, mean_index,
                                          W_pred, sc, E);

    final_kernel<<<(M + 255) / 256, 256, 0, stream>>>(sc, b_pred, (float*)d_out, M);
}

// Round 7
// 196.689 us; speedup vs baseline: 1.1997x; 1.0097x over previous
//
#include <hip/hip_runtime.h>

typedef unsigned short u16;
typedef unsigned int   u32;

typedef short short8 __attribute__((ext_vector_type(8)));
typedef float floatx4 __attribute__((ext_vector_type(4)));

#define CDIM 128
#define K_NEG_LOG2E -1.4426950408889634f
#define CNT_SCALE 16777216.0   // 2^24: packs (sum, count) into one f64

__device__ __forceinline__ float bf2f_lo(u32 h) {
    union { u32 u; float f; } v; v.u = h << 16; return v.f;
}
__device__ __forceinline__ float bf2f_hi(u32 h) {
    union { u32 u; float f; } v; v.u = h & 0xffff0000u; return v.f;
}
__device__ __forceinline__ u16 f2bf(float f) {
    union { float f; u32 u; } v; v.f = f;
    u32 u = v.u;
    return (u16)((u + 0x7FFFu + ((u >> 16) & 1u)) >> 16);  // RNE
}
__device__ __forceinline__ float sig_std(float x) {
    return __builtin_amdgcn_rcpf(1.0f + __builtin_amdgcn_exp2f(x * K_NEG_LOG2E));
}

// One launch: zero f64 accumulators, convert weights to pre-scaled bf16,
// and pack the four edge-index arrays into one int4 of BYTE OFFSETS.
__global__ __launch_bounds__(256) void prep_kernel(
    const float* __restrict__ Wstu, const float* __restrict__ Witem,
    u32* __restrict__ Wbf_pair, float4* __restrict__ zero4, int nZero4,
    const int* __restrict__ stu_track, const int* __restrict__ item_index,
    const int* __restrict__ conc_index, const int* __restrict__ mean_index,
    int4* __restrict__ idx4, int E)
{
    const int tid = blockIdx.x * blockDim.x + threadIdx.x;
    const int stride = gridDim.x * blockDim.x;
    for (int i = tid; i < 16384; i += stride) {
        const float* W = (i & 8192) ? (Witem - 16384) : Wstu;
        const int j = i * 2;
        u32 lo = f2bf(W[j]     * K_NEG_LOG2E);
        u32 hi = f2bf(W[j + 1] * K_NEG_LOG2E);
        Wbf_pair[i] = lo | (hi << 16);
    }
    const float4 z = {0.f, 0.f, 0.f, 0.f};
    for (int i = tid; i < nZero4; i += stride) zero4[i] = z;
    for (int e = tid; e < E; e += stride) {
        int4 t;
        t.x = stu_track[e]  << 8;   // 256 B rows
        t.y = item_index[e] << 8;   // 256 B rows
        t.z = conc_index[e] << 9;   // 512 B rows (cat)
        t.w = mean_index[e] << 3;   // f64 slots
        idx4[e] = t;
    }
}

// One wave computes a 32-row tile; stores exp2(proj + bias) in bf16.
__device__ __forceinline__ void proj_tile32(
    const float* __restrict__ X, const u16* __restrict__ Wbf,
    const float* __restrict__ bias, u16* __restrict__ out,
    int nrows, int ostride, int ooff, int row0, int lane)
{
    const int m = lane & 15;   // A-row / B-col / D-col
    const int g = lane >> 4;   // k-quad

    short8 a[2][4];
#pragma unroll
    for (int t = 0; t < 2; ++t) {
        int arow = row0 + t * 16 + m;
        if (arow >= nrows) arow = nrows - 1;   // clamp; stores masked below
        const float* xrow = X + (size_t)arow * CDIM;
#pragma unroll
        for (int s = 0; s < 4; ++s) {
            float4 f0 = *(const float4*)(xrow + s * 32 + g * 8);
            float4 f1 = *(const float4*)(xrow + s * 32 + g * 8 + 4);
            a[t][s][0] = (short)f2bf(f0.x); a[t][s][1] = (short)f2bf(f0.y);
            a[t][s][2] = (short)f2bf(f0.z); a[t][s][3] = (short)f2bf(f0.w);
            a[t][s][4] = (short)f2bf(f1.x); a[t][s][5] = (short)f2bf(f1.y);
            a[t][s][6] = (short)f2bf(f1.z); a[t][s][7] = (short)f2bf(f1.w);
        }
    }

#pragma unroll
    for (int ct = 0; ct < 8; ++ct) {
        const u16* wrow = Wbf + (size_t)(ct * 16 + m) * CDIM;
        floatx4 acc0 = {0.f, 0.f, 0.f, 0.f};
        floatx4 acc1 = {0.f, 0.f, 0.f, 0.f};
#pragma unroll
        for (int s = 0; s < 4; ++s) {
            short8 b = *(const short8*)(wrow + s * 32 + g * 8);
            acc0 = __builtin_amdgcn_mfma_f32_16x16x32_bf16(a[0][s], b, acc0, 0, 0, 0);
            acc1 = __builtin_amdgcn_mfma_f32_16x16x32_bf16(a[1][s], b, acc1, 0, 0, 0);
        }
        const int col = ct * 16 + m;           // D: col = lane&15
        const float badd = bias ? bias[col] * K_NEG_LOG2E : 0.f;
#pragma unroll
        for (int i = 0; i < 4; ++i) {
            int r0 = row0 + g * 4 + i;         // D: row = (lane>>4)*4 + reg
            if (r0 < nrows)
                out[(size_t)r0 * ostride + ooff + col] =
                    f2bf(__builtin_amdgcn_exp2f(acc0[i] + badd));
            int r1 = r0 + 16;
            if (r1 < nrows)
                out[(size_t)r1 * ostride + ooff + col] =
                    f2bf(__builtin_amdgcn_exp2f(acc1[i] + badd));
        }
    }
}

// All four projections in one launch; wave-uniform segment select.
__global__ __launch_bounds__(256) void proj4_kernel(
    const float* __restrict__ stu_x, const float* __restrict__ item_x,
    const float* __restrict__ conc_x,
    const u16* __restrict__ Wstu_bf, const u16* __restrict__ Witem_bf,
    const float* __restrict__ b_stu, const float* __restrict__ b_item,
    u16* __restrict__ stu_p, u16* __restrict__ item_p, u16* __restrict__ conc_cat,
    int NS, int NI, int NC)
{
    const int lane = threadIdx.x & 63;
    int w = blockIdx.x * 4 + (threadIdx.x >> 6);
    const int T0 = (NS + 31) / 32, T1 = (NI + 31) / 32, T2 = (NC + 31) / 32;

    if (w < T0) { proj_tile32(stu_x, Wstu_bf, nullptr, stu_p, NS, 128, 0, w * 32, lane); return; }
    w -= T0;
    if (w < T1) { proj_tile32(item_x, Witem_bf, nullptr, item_p, NI, 128, 0, w * 32, lane); return; }
    w -= T1;
    if (w < T2) { proj_tile32(conc_x, Wstu_bf, b_stu, conc_cat, NC, 256, 0, w * 32, lane); return; }
    w -= T2;
    if (w < T2) { proj_tile32(conc_x, Witem_bf, b_item, conc_cat, NC, 256, 128, w * 32, lane); return; }
}

// 16 lanes per edge, 4 edges per wave. Tables hold E = 2^(pre-scaled proj).
// Branchless clamped software pipeline (depth 1 data / depth 2 idx), ping-pong
// registers (no rotation movs), packed-f32 channel math, one f64 atomic/edge.
__global__ __launch_bounds__(256) void edge_kernel(
    const u16* __restrict__ stu_p, const u16* __restrict__ item_p,
    const u16* __restrict__ conc_cat,
    const int4* __restrict__ idx4,     // byte offsets {stu, item, conc, mean}
    const float* __restrict__ w_pred,
    double* __restrict__ sc, int E)
{
    const int lane = threadIdx.x & 63;
    const int sub  = lane & 15;      // position within edge
    const int g    = lane >> 4;      // edge within quad
    const int waveId = (int)((blockIdx.x * blockDim.x + threadIdx.x) >> 6);
    const int S      = (int)((gridDim.x * blockDim.x) >> 6);   // wave stride

    const float4 wA = ((const float4*)w_pred)[sub * 2];
    const float4 wB = ((const float4*)w_pred)[sub * 2 + 1];
    float2 w2[4];
    w2[0] = make_float2(wA.x, wA.y); w2[1] = make_float2(wA.z, wA.w);
    w2[2] = make_float2(wB.x, wB.y); w2[3] = make_float2(wB.z, wB.w);
    const u32 lane_off = (u32)sub * 16;

    const int nQuads = (E + 3) >> 2;
    int q = waveId;
    if (q >= nQuads) return;

    // always-safe index load: edge id clamped to E-1
    auto ldidx = [&](int qq) -> int4 {
        int e = qq * 4 + g;
        e = (e < E) ? e : (E - 1);
        return idx4[e];
    };
    auto compute = [&](const uint4& sv, const uint4& iv,
                       const uint4& ca, const uint4& cb,
                       const int4& I, int qq) {
        const u32 su[4] = {sv.x, sv.y, sv.z, sv.w};
        const u32 iu[4] = {iv.x, iv.y, iv.z, iv.w};
        const u32 au[4] = {ca.x, ca.y, ca.z, ca.w};
        const u32 bu[4] = {cb.x, cb.y, cb.z, cb.w};
        const float2 one = make_float2(1.f, 1.f);
        float2 vacc = make_float2(0.f, 0.f);
#pragma unroll
        for (int j = 0; j < 4; ++j) {
            float2 A  = make_float2(bf2f_lo(au[j]), bf2f_hi(au[j]));
            float2 Sx = make_float2(bf2f_lo(su[j]), bf2f_hi(su[j]));
            float2 B  = make_float2(bf2f_lo(bu[j]), bf2f_hi(bu[j]));
            float2 Ix = make_float2(bf2f_lo(iu[j]), bf2f_hi(iu[j]));
            float2 ea = A * Sx;                    // v_pk_mul_f32
            float2 eb = B * Ix;
            float2 den = (ea + one) * (eb + one);  // (1+ea)(1+eb)
            float2 num = eb - ea;
            float2 rd = make_float2(__builtin_amdgcn_rcpf(den.x),
                                    __builtin_amdgcn_rcpf(den.y));
            vacc += (num * rd) * w2[j];
        }
        float v = vacc.x + vacc.y;
        v += __shfl_xor(v, 1, 64);
        v += __shfl_xor(v, 2, 64);
        v += __shfl_xor(v, 4, 64);
        v += __shfl_xor(v, 8, 64);
        if (sub == 0 && (qq * 4 + g) < E)
            atomicAdd((double*)((char*)sc + (u32)I.w), (double)v + CNT_SCALE);
    };

#define GATH(I_, sv_, iv_, ca_, cb_) { \
        sv_ = *(const uint4*)((const char*)stu_p  + ((u32)(I_).x + lane_off)); \
        iv_ = *(const uint4*)((const char*)item_p + ((u32)(I_).y + lane_off)); \
        const char* cp_ = (const char*)conc_cat + ((u32)(I_).z + lane_off); \
        ca_ = *(const uint4*)cp_; cb_ = *(const uint4*)(cp_ + 256); }

    // prefetch: issue NEXT stage's gathers + idx two ahead, fence, compute CURRENT
#define STEP(DA, DB, IA, IB, IC) { \
        GATH(I##IB, sv##DB, iv##DB, ca##DB, cb##DB); \
        I##IC = ldidx(q + 2 * S); \
        __builtin_amdgcn_sched_barrier(0); \
        compute(sv##DA, iv##DA, ca##DA, cb##DA, I##IA, q); \
        q += S; \
        if (q >= nQuads) break; }

    // preamble
    int4 I0 = ldidx(q), I1 = ldidx(q + S), I2, I3;
    uint4 sv0, iv0, ca0, cb0, sv1, iv1, ca1, cb1;
    GATH(I0, sv0, iv0, ca0, cb0);

    for (;;) {
        STEP(0, 1, 0, 1, 2)   // compute D0/I0, gather I1->D1, load I2
        STEP(1, 0, 1, 2, 3)   // compute D1/I1, gather I2->D0, load I3
        STEP(0, 1, 2, 3, 0)   // compute D0/I2, gather I3->D1, load I0
        STEP(1, 0, 3, 0, 1)   // compute D1/I3, gather I0->D0, load I1
    }
#undef STEP
#undef GATH
}

__global__ __launch_bounds__(256) void final_kernel(
    const double* __restrict__ sc,
    const float* __restrict__ b_pred, float* __restrict__ out, int M)
{
    const int i = blockIdx.x * blockDim.x + threadIdx.x;
    if (i < M) {
        const double acc = sc[i];
        const double cnt = rint(acc * (1.0 / CNT_SCALE));   // |sum| << 2^23
        const double sum = acc - cnt * CNT_SCALE;
        const float mean = (float)(sum / fmax(cnt, 1.0));
        out[i] = sig_std(mean + b_pred[0]);
    }
}

extern "C" void kernel_launch(void* const* d_in, const int* in_sizes, int n_in,
                              void* d_out, int out_size, void* d_ws, size_t ws_size,
                              hipStream_t stream) {
    const float* stu_x    = (const float*)d_in[0];
    const float* item_x   = (const float*)d_in[1];
    const float* conc_x   = (const float*)d_in[2];
    const float* W_stu    = (const float*)d_in[3];
    const float* b_stu    = (const float*)d_in[4];
    const float* W_item   = (const float*)d_in[5];
    const float* b_item   = (const float*)d_in[6];
    const float* W_pred   = (const float*)d_in[7];
    const float* b_pred   = (const float*)d_in[8];
    const int* stu_track  = (const int*)d_in[9];
    const int* item_index = (const int*)d_in[10];
    const int* conc_index = (const int*)d_in[11];
    const int* mean_index = (const int*)d_in[12];

    const int NS = in_sizes[0] / CDIM;
    const int NI = in_sizes[1] / CDIM;
    const int NC = in_sizes[2] / CDIM;
    const int E  = in_sizes[9];
    const int M  = out_size;

    // workspace layout (all pieces 16B-aligned)
    double* sc     = (double*)d_ws;              // [M] packed (sum + cnt*2^24)
    u16* Wstu_bf   = (u16*)(sc + M);             // Wstu_bf || Witem_bf contiguous
    u16* Witem_bf  = Wstu_bf + CDIM * CDIM;
    u16* stu_p     = Witem_bf + CDIM * CDIM;
    u16* item_p    = stu_p  + (size_t)NS * CDIM;
    u16* conc_cat  = item_p + (size_t)NI * CDIM; // [NC][256]: exp2 stu | item side
    int4* idx4     = (int4*)(conc_cat + (size_t)NC * 256);

    const int nZero4 = (int)(((size_t)M * sizeof(double)) / 16);
    prep_kernel<<<1024, 256, 0, stream>>>(W_stu, W_item, (u32*)Wstu_bf,
                                          (float4*)sc, nZero4,
                                          stu_track, item_index, conc_index,
                                          mean_index, idx4, E);

    const int T0 = (NS + 31) / 32, T1 = (NI + 31) / 32, T2 = (NC + 31) / 32;
    const int totalWaves = T0 + T1 + 2 * T2;
    proj4_kernel<<<(totalWaves + 3) / 4, 256, 0, stream>>>(
        stu_x, item_x, conc_x, Wstu_bf, Witem_bf, b_stu, b_item,
        stu_p, item_p, conc_cat, NS, NI, NC);

    edge_kernel<<<4096, 256, 0, stream>>>(stu_p, item_p, conc_cat,
                                          idx4, W_pred, sc, E);

    final_kernel<<<(M + 255) / 256, 256, 0, stream>>>(sc, b_pred, (float*)d_out, M);
}